// Round 4
// baseline (150.841 us; speedup 1.0000x reference)
//
#include <hip/hip_runtime.h>

// ModuleCollect: out[i] = concat(x[i], masked_gather(x, idx[i,0..3]))
// x: [N, 256] f32, indices: [N,4] int (-1 = masked -> zeros)
// out: [N, 1280] f32
//
// One 64-lane wave per row; each lane moves one float4 per 256-float
// segment (64*4 = 256). Block = 256 threads = 4 waves = 4 rows.
//
// Cache policy:
//  - output stores: non-temporal (512 MB write-once; don't evict x)
//  - self-row load: non-temporal (102 MB streaming, touched exactly once
//    in sequence; don't let it evict gather-resident rows)
//  - gather loads: NORMAL, so x rows stay resident in L2/Infinity Cache
//    (x = 102 MB < 256 MB MALL; each row is re-read ~4x as a neighbor)

typedef float f32x4 __attribute__((ext_vector_type(4)));

#define D 256
#define D4 (D / 4)        // 64 f32x4 per row of x
#define OUTW (5 * D)      // 1280
#define OUTW4 (OUTW / 4)  // 320
#define ROWS_PER_BLOCK 4

__global__ __launch_bounds__(256) void collect_kernel(
    const f32x4* __restrict__ x4,      // [N * 64]
    const int*   __restrict__ indices, // [N * 4]
    f32x4*       __restrict__ out4,    // [N * 320]
    int n)
{
    const int wave = threadIdx.x >> 6;           // 0..3
    const int lane = threadIdx.x & 63;           // 0..63
    const int row  = blockIdx.x * ROWS_PER_BLOCK + wave;
    if (row >= n) return;

    const f32x4* xrow = x4 + (long)row * D4;
    f32x4* orow = out4 + (long)row * OUTW4;

    // indices are wave-uniform -> one broadcast transaction
    const int i0 = indices[row * 4 + 0];
    const int i1 = indices[row * 4 + 1];
    const int i2 = indices[row * 4 + 2];
    const int i3 = indices[row * 4 + 3];

    const f32x4 zero = (f32x4){0.f, 0.f, 0.f, 0.f};

    // self row: streaming read, bypass cache allocation
    f32x4 v_self = __builtin_nontemporal_load(&xrow[lane]);
    // gathers: normal cached reads (want residency in L2/MALL)
    f32x4 v0 = (i0 >= 0) ? x4[(long)i0 * D4 + lane] : zero;
    f32x4 v1 = (i1 >= 0) ? x4[(long)i1 * D4 + lane] : zero;
    f32x4 v2 = (i2 >= 0) ? x4[(long)i2 * D4 + lane] : zero;
    f32x4 v3 = (i3 >= 0) ? x4[(long)i3 * D4 + lane] : zero;

    __builtin_nontemporal_store(v_self, &orow[lane]);
    __builtin_nontemporal_store(v0, &orow[D4 * 1 + lane]);
    __builtin_nontemporal_store(v1, &orow[D4 * 2 + lane]);
    __builtin_nontemporal_store(v2, &orow[D4 * 3 + lane]);
    __builtin_nontemporal_store(v3, &orow[D4 * 4 + lane]);
}

extern "C" void kernel_launch(void* const* d_in, const int* in_sizes, int n_in,
                              void* d_out, int out_size, void* d_ws, size_t ws_size,
                              hipStream_t stream)
{
    const f32x4* x4 = (const f32x4*)d_in[0];
    const int* indices = (const int*)d_in[1];
    f32x4* out4 = (f32x4*)d_out;

    const int n = in_sizes[0] / D;  // 100000

    dim3 block(256);
    dim3 grid((n + ROWS_PER_BLOCK - 1) / ROWS_PER_BLOCK);
    collect_kernel<<<grid, block, 0, stream>>>(x4, indices, out4, n);
}

// Round 5
// 150.468 us; speedup vs baseline: 1.0025x; 1.0025x over previous
//
#include <hip/hip_runtime.h>

// ModuleCollect: out[i] = concat(x[i], masked_gather(x, idx[i,0..3]))
// x: [N, 256] f32, indices: [N,4] int (-1 = masked -> zeros)
// out: [N, 1280] f32
//
// Segmented 2-pass gather for Infinity-Cache locality:
//   pass p only executes gathers whose TARGET row is in x-segment p
//   (~51 MB, fits the 256 MB MALL with 5x headroom). Within a pass the
//   gather working set is MALL-resident, so each x row is fetched from
//   HBM ~once instead of ~5x.
//   pass 0 additionally: self-row copy (normal load if the row is in
//   segment 0 to prime the cache, nt-load otherwise) and zero-fill of
//   masked (-1) slots.
// All stores non-temporal (512 MB write-once stream must not evict x).
// All per-row branches are wave-uniform (indices are wave-uniform).

typedef float f32x4 __attribute__((ext_vector_type(4)));

#define D 256
#define D4 (D / 4)        // 64 f32x4 per row of x
#define OUTW4 (5 * D / 4) // 320 f32x4 per output row
#define ROWS_PER_BLOCK 4

__global__ __launch_bounds__(256) void collect_pass_kernel(
    const f32x4* __restrict__ x4,      // [N * 64]
    const int*   __restrict__ indices, // [N * 4]
    f32x4*       __restrict__ out4,    // [N * 320]
    int n, int seg_lo, int seg_hi, int do_self)
{
    const int wave = threadIdx.x >> 6;
    const int lane = threadIdx.x & 63;
    const int row  = blockIdx.x * ROWS_PER_BLOCK + wave;
    if (row >= n) return;

    f32x4* orow = out4 + (long)row * OUTW4;

    // wave-uniform neighbor indices
    int idx[4];
    idx[0] = indices[row * 4 + 0];
    idx[1] = indices[row * 4 + 1];
    idx[2] = indices[row * 4 + 2];
    idx[3] = indices[row * 4 + 3];

    const f32x4 zero = (f32x4){0.f, 0.f, 0.f, 0.f};

    if (do_self) {
        const f32x4* xrow = x4 + (long)row * D4;
        f32x4 v_self;
        if (row >= seg_lo && row < seg_hi) {
            v_self = xrow[lane];                         // prime cache
        } else {
            v_self = __builtin_nontemporal_load(&xrow[lane]);
        }
        __builtin_nontemporal_store(v_self, &orow[lane]);

        // zero-fill masked slots (only pass 0 touches them)
        #pragma unroll
        for (int s = 0; s < 4; ++s) {
            if (idx[s] < 0) {
                __builtin_nontemporal_store(zero, &orow[D4 * (1 + s) + lane]);
            }
        }
    }

    // gathers restricted to this pass's segment
    #pragma unroll
    for (int s = 0; s < 4; ++s) {
        const int t = idx[s];
        if (t >= seg_lo && t < seg_hi) {                 // wave-uniform branch
            f32x4 v = x4[(long)t * D4 + lane];           // normal cached load
            __builtin_nontemporal_store(v, &orow[D4 * (1 + s) + lane]);
        }
    }
}

extern "C" void kernel_launch(void* const* d_in, const int* in_sizes, int n_in,
                              void* d_out, int out_size, void* d_ws, size_t ws_size,
                              hipStream_t stream)
{
    const f32x4* x4 = (const f32x4*)d_in[0];
    const int* indices = (const int*)d_in[1];
    f32x4* out4 = (f32x4*)d_out;

    const int n = in_sizes[0] / D;   // 100000
    const int half = n / 2;          // 50000

    dim3 block(256);
    dim3 grid((n + ROWS_PER_BLOCK - 1) / ROWS_PER_BLOCK);

    // pass 0: self-copy + masked zero-fill + gathers targeting [0, half)
    collect_pass_kernel<<<grid, block, 0, stream>>>(x4, indices, out4, n,
                                                    0, half, 1);
    // pass 1: gathers targeting [half, n)
    collect_pass_kernel<<<grid, block, 0, stream>>>(x4, indices, out4, n,
                                                    half, n, 0);
}

// Round 6
// 145.778 us; speedup vs baseline: 1.0347x; 1.0322x over previous
//
#include <hip/hip_runtime.h>

// ModuleCollect: out[i] = concat(x[i], masked_gather(x, idx[i,0..3]))
// x: [N, 256] f32, indices: [N,4] int (-1 = masked -> zeros), out: [N, 1280] f32
//
// INVERTED-INDEX formulation: forward gather reads x ~5x (512 MB) because
// the random gathers get no cache help (measured: 2-pass segmentation was
// null). Instead, build per-source-row reference lists, then one wave per
// SOURCE row reads x[r] once and scatters it to all referencing output
// segments. Read traffic drops 512 MB -> ~117 MB structurally.
//
//   K1 zero_counts:   counts[N]=0, ovf_cnt=0
//   K2 build_buckets: for each of 4N entries e: t=idx[e]; if t>=0:
//                     pos=atomicAdd(count[t]); bucket[t*16+pos]=e (or overflow)
//   K3 scatter:       wave r: v=x[r] (nt-load, 1KB); store self seg;
//                     zero own masked slots; for each bucket entry write v
//                     to out[dest].seg[slot+1]. All stores nt, 1KB-aligned.
//   K4 overflow_fixup: forward-gather the (expected ~0) overflow entries.
//
// Bucket order is atomic-nondeterministic but the (dest,slot)->value map is
// exact, so d_out is deterministic. counts/ovf re-zeroed every call.
// Falls back to the plain forward kernel if ws_size is too small.

typedef float f32x4 __attribute__((ext_vector_type(4)));

#define D 256
#define D4 (D / 4)        // 64 f32x4 per row of x
#define OUTW4 (5 * D / 4) // 320 f32x4 per output row
#define CAP 16            // bucket capacity; Poisson(4) tail beyond 16 ~ 5e-6/row
#define OVF_CAP 65536

__global__ __launch_bounds__(256) void zero_counts_kernel(int* counts, int* ovf_cnt, int n)
{
    int i = blockIdx.x * blockDim.x + threadIdx.x;
    if (i == 0) *ovf_cnt = 0;
    if (i < n) counts[i] = 0;
}

__global__ __launch_bounds__(256) void build_buckets_kernel(
    const int* __restrict__ indices, int* counts, int* buckets,
    int* ovf, int* ovf_cnt, int n4)
{
    int e = blockIdx.x * blockDim.x + threadIdx.x;
    if (e >= n4) return;
    int t = indices[e];
    if (t < 0) return;
    int pos = atomicAdd(&counts[t], 1);
    if (pos < CAP) {
        buckets[t * CAP + pos] = e;      // e encodes dest*4+slot
    } else {
        int o = atomicAdd(ovf_cnt, 1);
        if (o < OVF_CAP) ovf[o] = e;
    }
}

__global__ __launch_bounds__(256) void scatter_kernel(
    const f32x4* __restrict__ x4,       // [N * 64]
    const int*   __restrict__ indices,  // [N * 4]
    const int*   __restrict__ counts,
    const int*   __restrict__ buckets,
    f32x4*       __restrict__ out4,     // [N * 320]
    int n)
{
    const int wave = threadIdx.x >> 6;
    const int lane = threadIdx.x & 63;
    const int r = blockIdx.x * 4 + wave;
    if (r >= n) return;

    // source row, read exactly once kernel-wide
    const f32x4 v = __builtin_nontemporal_load(&x4[(long)r * D4 + lane]);

    // self segment
    __builtin_nontemporal_store(v, &out4[(long)r * OUTW4 + lane]);

    // zero-fill own masked slots (rare: P(idx==-1) ~ 1e-5)
    const f32x4 zero = (f32x4){0.f, 0.f, 0.f, 0.f};
    #pragma unroll
    for (int s = 0; s < 4; ++s) {
        if (indices[r * 4 + s] < 0)
            __builtin_nontemporal_store(zero, &out4[(long)r * OUTW4 + (1 + s) * D4 + lane]);
    }

    // scatter to referencing outputs
    int cnt = counts[r];
    if (cnt > CAP) cnt = CAP;
    for (int j = 0; j < cnt; ++j) {
        int e = buckets[r * CAP + j];
        int dest = e >> 2, slot = e & 3;
        __builtin_nontemporal_store(v, &out4[(long)dest * OUTW4 + (1 + slot) * D4 + lane]);
    }
}

__global__ __launch_bounds__(256) void overflow_fixup_kernel(
    const f32x4* __restrict__ x4, const int* __restrict__ indices,
    const int* __restrict__ ovf, const int* __restrict__ ovf_cnt,
    f32x4* __restrict__ out4)
{
    const int wave = threadIdx.x >> 6;
    const int lane = threadIdx.x & 63;
    const int gw = blockIdx.x * 4 + wave;
    const int nwaves = gridDim.x * 4;
    int cnt = *ovf_cnt;
    if (cnt > OVF_CAP) cnt = OVF_CAP;
    for (int i = gw; i < cnt; i += nwaves) {
        int e = ovf[i];
        int row = e >> 2, slot = e & 3;
        int t = indices[e];                      // >= 0 by construction
        f32x4 v = x4[(long)t * D4 + lane];
        __builtin_nontemporal_store(v, &out4[(long)row * OUTW4 + (1 + slot) * D4 + lane]);
    }
}

// ---- fallback: plain forward kernel (round-3 version) ----
__global__ __launch_bounds__(256) void collect_fwd_kernel(
    const f32x4* __restrict__ x4, const int* __restrict__ indices,
    f32x4* __restrict__ out4, int n)
{
    const int wave = threadIdx.x >> 6;
    const int lane = threadIdx.x & 63;
    const int row  = blockIdx.x * 4 + wave;
    if (row >= n) return;
    const f32x4* xrow = x4 + (long)row * D4;
    f32x4* orow = out4 + (long)row * OUTW4;
    const int i0 = indices[row * 4 + 0];
    const int i1 = indices[row * 4 + 1];
    const int i2 = indices[row * 4 + 2];
    const int i3 = indices[row * 4 + 3];
    const f32x4 zero = (f32x4){0.f, 0.f, 0.f, 0.f};
    f32x4 v_self = xrow[lane];
    f32x4 v0 = (i0 >= 0) ? x4[(long)i0 * D4 + lane] : zero;
    f32x4 v1 = (i1 >= 0) ? x4[(long)i1 * D4 + lane] : zero;
    f32x4 v2 = (i2 >= 0) ? x4[(long)i2 * D4 + lane] : zero;
    f32x4 v3 = (i3 >= 0) ? x4[(long)i3 * D4 + lane] : zero;
    __builtin_nontemporal_store(v_self, &orow[lane]);
    __builtin_nontemporal_store(v0, &orow[D4 * 1 + lane]);
    __builtin_nontemporal_store(v1, &orow[D4 * 2 + lane]);
    __builtin_nontemporal_store(v2, &orow[D4 * 3 + lane]);
    __builtin_nontemporal_store(v3, &orow[D4 * 4 + lane]);
}

extern "C" void kernel_launch(void* const* d_in, const int* in_sizes, int n_in,
                              void* d_out, int out_size, void* d_ws, size_t ws_size,
                              hipStream_t stream)
{
    const f32x4* x4 = (const f32x4*)d_in[0];
    const int* indices = (const int*)d_in[1];
    f32x4* out4 = (f32x4*)d_out;

    const int n  = in_sizes[0] / D;   // 100000
    const int n4 = in_sizes[1];       // 400000

    // ws layout (64B-aligned fields)
    size_t off_counts  = 0;                                   // n ints
    size_t off_ovfcnt  = (size_t)((n * 4 + 63) / 64) * 64;    // 1 int
    size_t off_ovf     = off_ovfcnt + 64;                     // OVF_CAP ints
    size_t off_buckets = off_ovf + (size_t)OVF_CAP * 4;       // n*CAP ints
    size_t need = off_buckets + (size_t)n * CAP * 4;

    dim3 block(256);

    if (ws_size < need) {
        // scratch too small: forward gather fallback
        collect_fwd_kernel<<<dim3((n + 3) / 4), block, 0, stream>>>(x4, indices, out4, n);
        return;
    }

    char* ws = (char*)d_ws;
    int* counts  = (int*)(ws + off_counts);
    int* ovf_cnt = (int*)(ws + off_ovfcnt);
    int* ovf     = (int*)(ws + off_ovf);
    int* buckets = (int*)(ws + off_buckets);

    zero_counts_kernel<<<dim3((n + 255) / 256), block, 0, stream>>>(counts, ovf_cnt, n);
    build_buckets_kernel<<<dim3((n4 + 255) / 256), block, 0, stream>>>(
        indices, counts, buckets, ovf, ovf_cnt, n4);
    scatter_kernel<<<dim3((n + 3) / 4), block, 0, stream>>>(
        x4, indices, counts, buckets, out4, n);
    overflow_fixup_kernel<<<dim3(8), block, 0, stream>>>(
        x4, indices, ovf, ovf_cnt, out4);
}